// Round 8
// baseline (342.807 us; speedup 1.0000x reference)
//
#include <hip/hip_runtime.h>

typedef __bf16 bf16;
typedef __bf16 bf16x4 __attribute__((ext_vector_type(4)));
typedef __bf16 bf16x8 __attribute__((ext_vector_type(8)));
typedef float f32x4 __attribute__((ext_vector_type(4)));

#define CCH 128  // channels (all layers 128 -> 128)

// ---- prep (merged): weights -> MFMA-packed bf16; centers -> MFMA-packed ----
// weight pack: [((kt*4 + c)*8 + og)*512 + lane*8 + e], o = og*16 + (lane&15),
// i = c*32 + (lane>>4)*8 + e  => A-fragment load = one contiguous 1KB burst.
// center pack (cpk): [(j*4 + og)*512 + lane*8 + e], center k = og*16+(lane&15),
// feature f = j*32 + (lane>>4)*8 + e, f = l*128 + o_ch (l-major to match zmem).
__global__ void k_prep_all(const float* __restrict__ w1, const float* __restrict__ w2,
                           const float* __restrict__ w3, const float* __restrict__ w4,
                           const float* __restrict__ cen,
                           bf16* __restrict__ o1, bf16* __restrict__ o2,
                           bf16* __restrict__ o3, bf16* __restrict__ o4,
                           bf16* __restrict__ cpk, float* __restrict__ cc) {
    __shared__ float red[256];
    int tid = threadIdx.x;
    int bid = blockIdx.x;
    if (bid < 2432) {
        int idx = bid * 256 + tid;
        const float* src; bf16* dst; int Kw; int r = idx;
        if (r < 15 * 16384) { src = w1; dst = o1; Kw = 15; }
        else if ((r -= 15 * 16384) < 12 * 16384) { src = w2; dst = o2; Kw = 12; }
        else if ((r -= 12 * 16384) < 7 * 16384) { src = w3; dst = o3; Kw = 7; }
        else if ((r -= 7 * 16384) < 4 * 16384) { src = w4; dst = o4; Kw = 4; }
        else return;
        int e = r & 7, lane = (r >> 3) & 63, og = (r >> 9) & 7, c = (r >> 12) & 3, kt = r >> 14;
        int o = og * 16 + (lane & 15);
        int i = c * 32 + (lane >> 4) * 8 + e;
        dst[r] = (bf16)src[(o * 128 + i) * Kw + kt];
    } else if (bid < 2432 + 256) {
        // center MFMA pack: block j fills 4 og x 512 elems
        int j = bid - 2432;
        int l = j >> 2;            // feature row (position)
#pragma unroll
        for (int it = 0; it < 8; ++it) {
            int u = tid + it * 256;
            int og = u >> 9, r9 = u & 511;
            int lane = r9 >> 3, e = r9 & 7;
            int k = og * 16 + (lane & 15);
            int oc = (j & 3) * 32 + (lane >> 4) * 8 + e;
            float v = (l < 59) ? cen[k * 7552 + oc * 59 + l] : 0.f;
            cpk[(((size_t)(j * 4 + og)) << 9) + r9] = (bf16)v;
        }
    } else {
        // ||c||^2 from the bf16-rounded center values
        int k = bid - (2432 + 256);
        float s = 0.f;
        for (int idx = tid; idx < 8192; idx += 256) {
            int l = idx >> 7;
            int o = idx & 127;
            if (l < 59) {
                float fv = (float)(bf16)cen[k * 7552 + o * 59 + l];
                s += fv * fv;
            }
        }
        red[tid] = s;
        __syncthreads();
        for (int st = 128; st > 0; st >>= 1) {
            if (tid < st) red[tid] += red[tid + st];
            __syncthreads();
        }
        if (tid == 0) cc[k] = red[0];
    }
}

// ---- conv1, fused x transpose (round-1 best config, unchanged) ----
__global__ __launch_bounds__(256, 4) void k_conv1(
    const float* __restrict__ x, const bf16* __restrict__ wTp,
    const float* __restrict__ bias, bf16* __restrict__ out) {
    constexpr int KW = 15, LT = 128, PH = 2, OUT_ROWS = 512;
    constexpr int P = (LT - 1) * 2 + KW;   // 269 input positions needed
    constexpr int KC = 2;                  // 32-chunks per phase
    constexpr int RS = 64;                 // LDS row stride (elems)
    constexpr int NLT = LT / 16;           // 8
    constexpr int ESE = 136;               // epilogue [l][o] stride
    constexpr int SMELE = (P * RS > LT * ESE) ? P * RS : LT * ESE;  // 17408
    constexpr int NJ = KW * KC;            // 30
    __shared__ __align__(16) bf16 smem[SMELE];

    const int n = blockIdx.y;
    const int l0 = blockIdx.x * LT;
    const int p0 = l0 * 2;
    const int tid = threadIdx.x;
    const int wid = tid >> 6;
    const int lane = tid & 63;
    const int quad = lane >> 4;
    const int l15 = lane & 15;
    const int og0 = wid * 2;               // wave owns o [wid*32, wid*32+32)

    f32x4 acc[2][NLT];
#pragma unroll
    for (int a = 0; a < 2; ++a)
#pragma unroll
        for (int b = 0; b < NLT; ++b) acc[a][b] = (f32x4){0.f, 0.f, 0.f, 0.f};

    bf16x8 afr[2][2];
    const bf16* wbase = wTp + (size_t)lane * 8;
    afr[0][0] = *(const bf16x8*)(wbase + ((size_t)(og0 + 0) << 9));
    afr[0][1] = *(const bf16x8*)(wbase + ((size_t)(og0 + 1) << 9));

    const int cst = tid >> 2;              // channel within phase (0..63)
    const int qw = tid & 3;                // quad within 16-pos block

#pragma unroll 1
    for (int ph = 0; ph < PH; ++ph) {
        if (ph) __syncthreads();  // protect smem against overwrite

        const float* bch = x + ((size_t)(n * 128 + ph * 64 + cst)) * 1024;
#pragma unroll 4
        for (int it = 0; it < 17; ++it) {   // 17*16 = 272 positions (>=269)
            int pp = it * 16 + qw * 4;
            int gp = p0 + pp;
            f32x4 t;
            if (gp + 3 < 1024) {
                t = *(const f32x4*)(bch + gp);
            } else {
#pragma unroll
                for (int e = 0; e < 4; ++e) t[e] = (gp + e < 1024) ? bch[gp + e] : 0.f;
            }
#pragma unroll
            for (int e = 0; e < 4; ++e) {
                int ppe = pp + e;
                int sc8 = (((cst >> 3) ^ ((ppe >> 1) & 7)) << 3) | (cst & 7);
                smem[ppe * RS + sc8] = (bf16)t[e];
            }
        }
        __syncthreads();

#pragma unroll 2
        for (int j = 0; j < NJ; ++j) {
            int nj = j + 1, nph = ph;
            if (nj == NJ) { nj = 0; ++nph; }
            if (nph < PH) {
                int kt1 = nj >> 1;
                int c1 = (nj & (KC - 1)) + nph * KC;
                const bf16* wp = wbase + ((size_t)((kt1 * 4 + c1) * 8 + og0) << 9);
                afr[(j + 1) & 1][0] = *(const bf16x8*)(wp);
                afr[(j + 1) & 1][1] = *(const bf16x8*)(wp + 512);
            }
            const int kt = j >> 1;
            const int c16l = (j & (KC - 1)) * 4 + quad;
#pragma unroll
            for (int lt = 0; lt < NLT; ++lt) {
                int p = (lt * 16 + l15) * 2 + kt;
                int sc = c16l ^ ((p >> 1) & 7);
                bf16x8 bfr = *(const bf16x8*)(smem + p * RS + sc * 8);
                acc[0][lt] = __builtin_amdgcn_mfma_f32_16x16x32_bf16(
                    afr[j & 1][0], bfr, acc[0][lt], 0, 0, 0);
                acc[1][lt] = __builtin_amdgcn_mfma_f32_16x16x32_bf16(
                    afr[j & 1][1], bfr, acc[1][lt], 0, 0, 0);
            }
        }
    }

    __syncthreads();
#pragma unroll
    for (int ot = 0; ot < 2; ++ot) {
        const int o0 = wid * 32 + ot * 16 + quad * 4;
        const f32x4 bv = *(const f32x4*)(bias + o0);
#pragma unroll
        for (int lt = 0; lt < NLT; ++lt) {
            const int l = lt * 16 + l15;
            bf16x4 pk;
#pragma unroll
            for (int r = 0; r < 4; ++r) {
                float v = acc[ot][lt][r] + bv[r];
                v = (v > 0.f) ? v : 0.1f * v;
                pk[r] = (bf16)v;
            }
            *(bf16x4*)(smem + l * ESE + o0) = pk;
        }
    }
    __syncthreads();
    constexpr int SNIT = LT * 16 / 256;
    bf16* op = out + ((size_t)n * OUT_ROWS + l0) * CCH;
#pragma unroll
    for (int it = 0; it < SNIT; ++it) {
        int u = tid + it * 256;
        int l = u >> 4;
        int g = u & 15;
        *(bf16x8*)(op + l * CCH + g * 8) = *(const bf16x8*)(smem + l * ESE + g * 8);
    }
}

// ---- fused conv2+conv3+conv4+distances: ONE block per n, 1024 threads ----
// 16 waves = 4 waves/SIMD: the fused chain was latency-bound at 2 waves/SIMD.
// conv2/conv3: wave = (row-group of 16) x (och half), B-dup 2.
// conv4: (row-group of 16) x (och quarter). dist: (K quarter) x (center group).
__global__ __launch_bounds__(1024, 1) void k_fused234(
    const bf16* __restrict__ h1g, const bf16* __restrict__ wT2,
    const bf16* __restrict__ wT3, const bf16* __restrict__ wT4,
    const float* __restrict__ b2, const float* __restrict__ b3,
    const float* __restrict__ b4, const bf16* __restrict__ cpk,
    const float* __restrict__ cc, float* __restrict__ out) {
    // LDS plan (bf16 elems):
    //  region A (34048 el): sbuf 266x128 during conv2; then h3 130x128 (16640)
    //                       + zmem 64x136 (8704) at offset 16640
    //  region B (33536 el): h2 262x128 (rows 256+ zero-initialized)
    __shared__ __align__(16) bf16 lds[34048 + 33536];
    __shared__ float d2p[4][64];
    __shared__ float zred[16];
    bf16* sbuf = lds;
    bf16* h2   = lds + 34048;
    bf16* h3   = lds;           // after conv2
    bf16* zmem = lds + 16640;   // after conv2

    const int n = blockIdx.x;
    const int tid = threadIdx.x;
    const int wid = tid >> 6;     // 0..15
    const int lane = tid & 63;
    const int quad = lane >> 4;
    const int l15 = lane & 15;

    // zero junk h2 rows 256..261 (read by conv3 tail, never written)
    if (tid < 96) *(f32x4*)(h2 + 256 * 128 + tid * 8) = (f32x4){0.f, 0.f, 0.f, 0.f};

    // ================= conv2: h1(global) -> h2(LDS), K=12, LeakyReLU ======
    // wave (rg=wid>>1: rows rg*16..+15 of the 128-row stage, oh=wid&1: 4 og)
    {
        const int oh = wid & 1;
        const int rg = wid >> 1;          // 0..7
        const bf16* w2base = wT2 + (size_t)lane * 8 + ((size_t)(oh * 4) << 9);
        const bf16* base = h1g + (size_t)n * 512 * 128;
        constexpr int NJ2 = 48;                 // 12 kt x 4 c
#pragma unroll 1
        for (int s = 0; s < 2; ++s) {
            if (s) __syncthreads();   // all conv2(0) sbuf reads done
            // stage h1 rows [s*256, s*256+266) -> sbuf (swizzled ds_write)
#pragma unroll
            for (int it = 0; it < 5; ++it) {
                int u = tid + it * 1024;
                if (u < 266 * 16) {
                    int p = u >> 4, c = u & 15;
                    int prow = s * 256 + p; if (prow > 511) prow = 511;
                    bf16x8 t = *(const bf16x8*)(base + (size_t)prow * 128 + c * 8);
                    int sc = (c & 8) | ((c & 7) ^ ((p >> 1) & 7));
                    *(bf16x8*)(sbuf + p * 128 + sc * 8) = t;
                }
            }
            __syncthreads();

            f32x4 acc[4];
#pragma unroll
            for (int a = 0; a < 4; ++a) acc[a] = (f32x4){0.f, 0.f, 0.f, 0.f};
            bf16x8 afr[2][4];
#pragma unroll
            for (int a = 0; a < 4; ++a)
                afr[0][a] = *(const bf16x8*)(w2base + ((size_t)a << 9));
#pragma unroll 2
            for (int j = 0; j < NJ2; ++j) {
                if (j + 1 < NJ2) {
                    int kt1 = (j + 1) >> 2, c1 = (j + 1) & 3;
                    const bf16* wp = w2base + ((size_t)((kt1 * 4 + c1) * 8) << 9);
#pragma unroll
                    for (int a = 0; a < 4; ++a)
                        afr[(j + 1) & 1][a] = *(const bf16x8*)(wp + ((size_t)a << 9));
                }
                int kt = j >> 2;
                int c16l = (j & 3) * 4 + quad;
                int p = (rg * 16 + l15) * 2 + kt;   // local sbuf row <= 265
                int sc = (c16l & 8) | ((c16l & 7) ^ ((p >> 1) & 7));
                bf16x8 bfr = *(const bf16x8*)(sbuf + p * 128 + sc * 8);
#pragma unroll
                for (int a = 0; a < 4; ++a)
                    acc[a] = __builtin_amdgcn_mfma_f32_16x16x32_bf16(
                        afr[j & 1][a], bfr, acc[a], 0, 0, 0);
            }
            // epilogue -> h2 (swizzled layout conv3 expects), LeakyReLU
            int l = s * 128 + rg * 16 + l15;   // h2 row 0..255
#pragma unroll
            for (int a = 0; a < 4; ++a) {
                int o0 = (oh * 4 + a) * 16 + quad * 4;
                f32x4 bv = *(const f32x4*)(b2 + o0);
                int c = o0 >> 3;
                bf16x4 pk;
#pragma unroll
                for (int r = 0; r < 4; ++r) {
                    float v = acc[a][r] + bv[r];
                    v = (v > 0.f) ? v : 0.1f * v;
                    pk[r] = (bf16)v;
                }
                int sc = (c & 8) | ((c & 7) ^ ((l >> 1) & 7));
                *(bf16x4*)(h2 + l * 128 + sc * 8 + (o0 & 7)) = pk;
            }
        }
        __syncthreads();
    }

    // ================= conv3: h2(LDS) -> h3(LDS), K=7, LeakyReLU ==========
    // wave (rg=wid>>1: rows rg*16..+15, oh=wid&1: 4 og)
    {
        // zero junk h3 rows 128..129 (read by conv4 tail); sbuf dead now
        if (tid < 32) *(f32x4*)(h3 + 128 * 128 + tid * 8) = (f32x4){0.f, 0.f, 0.f, 0.f};
        const int oh = wid & 1;
        const int rg = wid >> 1;          // 0..7
        const bf16* w3base = wT3 + (size_t)lane * 8 + ((size_t)(oh * 4) << 9);
        constexpr int NJ3 = 28;              // 7 kt x 4 c
        f32x4 acc[4];
#pragma unroll
        for (int a = 0; a < 4; ++a) acc[a] = (f32x4){0.f, 0.f, 0.f, 0.f};
        bf16x8 afr[2][4];
#pragma unroll
        for (int a = 0; a < 4; ++a)
            afr[0][a] = *(const bf16x8*)(w3base + ((size_t)a << 9));
#pragma unroll 2
        for (int j = 0; j < NJ3; ++j) {
            if (j + 1 < NJ3) {
                int kt1 = (j + 1) >> 2, c1 = (j + 1) & 3;
                const bf16* wp = w3base + ((size_t)((kt1 * 4 + c1) * 8) << 9);
#pragma unroll
                for (int a = 0; a < 4; ++a)
                    afr[(j + 1) & 1][a] = *(const bf16x8*)(wp + ((size_t)a << 9));
            }
            int kt = j >> 2;
            int c16l = (j & 3) * 4 + quad;
            int p = (rg * 16 + l15) * 2 + kt;   // h2 row <= 260
            int sc = (c16l & 8) | ((c16l & 7) ^ ((p >> 1) & 7));
            bf16x8 bfr = *(const bf16x8*)(h2 + p * 128 + sc * 8);
#pragma unroll
            for (int a = 0; a < 4; ++a)
                acc[a] = __builtin_amdgcn_mfma_f32_16x16x32_bf16(
                    afr[j & 1][a], bfr, acc[a], 0, 0, 0);
        }
        __syncthreads();
        // epilogue -> h3 (swizzled layout conv4 expects), LeakyReLU
        int l = rg * 16 + l15;   // h3 row 0..127
#pragma unroll
        for (int a = 0; a < 4; ++a) {
            int o0 = (oh * 4 + a) * 16 + quad * 4;
            f32x4 bv = *(const f32x4*)(b3 + o0);
            int c = o0 >> 3;
            bf16x4 pk;
#pragma unroll
            for (int r = 0; r < 4; ++r) {
                float v = acc[a][r] + bv[r];
                v = (v > 0.f) ? v : 0.1f * v;
                pk[r] = (bf16)v;
            }
            int sc = (c & 8) | ((c & 7) ^ ((l >> 1) & 7));
            *(bf16x4*)(h3 + l * 128 + sc * 8 + (o0 & 7)) = pk;
        }
    }
    __syncthreads();

    // ================= conv4: h3(LDS) -> zmem, no act, zero-pad l>=59 =====
    // wave (rg=wid&3: rows rg*16..+15, oq=wid>>2: og pair oq*2..oq*2+1)
    {
        const int rg = wid & 3;
        const int oq = wid >> 2;          // 0..3
        f32x4 acc[2];
#pragma unroll
        for (int a = 0; a < 2; ++a) acc[a] = (f32x4){0.f, 0.f, 0.f, 0.f};
        bf16x8 afr[2][2];
        const bf16* w4base = wT4 + (size_t)lane * 8 + ((size_t)(oq * 2) << 9);
#pragma unroll
        for (int a = 0; a < 2; ++a)
            afr[0][a] = *(const bf16x8*)(w4base + ((size_t)a << 9));
        constexpr int NJ4 = 16;              // 4 kt x 4 c
#pragma unroll 2
        for (int j = 0; j < NJ4; ++j) {
            if (j + 1 < NJ4) {
                int kt1 = (j + 1) >> 2, c1 = (j + 1) & 3;
                const bf16* wp = w4base + ((size_t)((kt1 * 4 + c1) * 8) << 9);
#pragma unroll
                for (int a = 0; a < 2; ++a)
                    afr[(j + 1) & 1][a] = *(const bf16x8*)(wp + ((size_t)a << 9));
            }
            int kt = j >> 2;
            int c16l = (j & 3) * 4 + quad;
            int p = (rg * 16 + l15) * 2 + kt;   // h3 row <= 129
            int sc = (c16l & 8) | ((c16l & 7) ^ ((p >> 1) & 7));
            bf16x8 bfr = *(const bf16x8*)(h3 + p * 128 + sc * 8);
#pragma unroll
            for (int a = 0; a < 2; ++a)
                acc[a] = __builtin_amdgcn_mfma_f32_16x16x32_bf16(
                    afr[j & 1][a], bfr, acc[a], 0, 0, 0);
        }
        // epilogue -> z bf16 [l][o] (stride 136), zeros l>=59; accumulate z2
        const int l = rg * 16 + l15;
        float s2 = 0.f;
#pragma unroll
        for (int a = 0; a < 2; ++a) {
            const int o0 = (oq * 2 + a) * 16 + quad * 4;
            const f32x4 bv = *(const f32x4*)(b4 + o0);
            bf16x4 pk;
#pragma unroll
            for (int r = 0; r < 4; ++r) {
                float v = acc[a][r] + bv[r];
                pk[r] = (l < 59) ? (bf16)v : (bf16)0.f;
                float zf = (float)pk[r];
                s2 += zf * zf;
            }
            *(bf16x4*)(zmem + l * 136 + o0) = pk;
        }
        // ||z||^2: wave reduce, then one slot per wave
#pragma unroll
        for (int o = 32; o > 0; o >>= 1) s2 += __shfl_xor(s2, o);
        if (lane == 0) zred[wid] = s2;
    }
    __syncthreads();

    // ================= distances via MFMA: zc[k] = sum_f C[k][f] z[f] ======
    // wave = (K quarter kq) x (center group og). A = packed centers (1KB
    // contiguous burst per j from L2); B = z broadcast (per-quad uniform 16B
    // LDS read -> bank broadcast). D row m = quad*4+r -> center og*16+m.
    {
        const int og = wid & 3;
        const int kq = wid >> 2;          // 0..3
        const bf16* cb = cpk + ((size_t)og << 9) + (size_t)lane * 8;
        f32x4 acc = (f32x4){0.f, 0.f, 0.f, 0.f};
        const int j0 = kq * 64;
        bf16x8 af[4];
#pragma unroll
        for (int q = 0; q < 4; ++q)
            af[q] = *(const bf16x8*)(cb + ((size_t)(j0 + q) << 11));
#pragma unroll 4
        for (int jj = 0; jj < 64; ++jj) {
            bf16x8 a = af[jj & 3];
            if (jj + 4 < 64)
                af[jj & 3] = *(const bf16x8*)(cb + ((size_t)(j0 + jj + 4) << 11));
            int l = kq * 16 + (jj >> 2);
            int off = (jj & 3) * 32 + quad * 8;
            bf16x8 b = *(const bf16x8*)(zmem + l * 136 + off);
            acc = __builtin_amdgcn_mfma_f32_16x16x32_bf16(a, b, acc, 0, 0, 0);
        }
        if (l15 == 0) {
#pragma unroll
            for (int r = 0; r < 4; ++r) d2p[kq][og * 16 + quad * 4 + r] = acc[r];
        }
    }
    __syncthreads();

    if (tid < 64) {
        float zc = d2p[0][tid] + d2p[1][tid] + d2p[2][tid] + d2p[3][tid];
        float z2 = 0.f;
#pragma unroll
        for (int w = 0; w < 16; ++w) z2 += zred[w];
        float d2v = z2 + cc[tid] - 2.f * zc;
        float q = 1.f / (1.f + d2v);  // ALPHA=1, exponent (ALPHA+1)/2 == 1
        float tot = q;
#pragma unroll
        for (int o = 32; o > 0; o >>= 1) tot += __shfl_xor(tot, o);
        out[n * 64 + tid] = q / tot;
    }
}

// ---------------- launcher ----------------
extern "C" void kernel_launch(void* const* d_in, const int* in_sizes, int n_in,
                              void* d_out, int out_size, void* d_ws, size_t ws_size,
                              hipStream_t stream) {
    (void)in_sizes; (void)n_in; (void)out_size; (void)ws_size;
    const float* x   = (const float*)d_in[0];
    const float* w1  = (const float*)d_in[1];
    const float* b1  = (const float*)d_in[2];
    const float* w2  = (const float*)d_in[3];
    const float* b2  = (const float*)d_in[4];
    const float* w3  = (const float*)d_in[5];
    const float* b3  = (const float*)d_in[6];
    const float* w4  = (const float*)d_in[7];
    const float* b4  = (const float*)d_in[8];
    const float* cen = (const float*)d_in[9];
    float* out = (float*)d_out;

    char* ws = (char*)d_ws;
    size_t off = 0;
    auto alloc = [&](size_t bytes) -> void* {
        void* p = ws + off;
        off += (bytes + 255) & ~(size_t)255;
        return p;
    };
    bf16* wT1 = (bf16*)alloc((size_t)15 * 16384 * sizeof(bf16));
    bf16* wT2 = (bf16*)alloc((size_t)12 * 16384 * sizeof(bf16));
    bf16* wT3 = (bf16*)alloc((size_t)7 * 16384 * sizeof(bf16));
    bf16* wT4 = (bf16*)alloc((size_t)4 * 16384 * sizeof(bf16));
    bf16* cpk = (bf16*)alloc((size_t)1024 * 512 * sizeof(bf16));  // 1 MB packed centers
    float* cc = (float*)alloc(64 * sizeof(float));
    bf16* h1  = (bf16*)alloc((size_t)256 * 512 * 128 * sizeof(bf16));
    (void)alloc((size_t)1 << 20);  // slack: tile overreads stay in-bounds

    // prep: 2432 wall blocks + 256 center-pack blocks + 64 cc blocks
    k_prep_all<<<2432 + 256 + 64, 256, 0, stream>>>(w1, w2, w3, w4, cen,
                                                    wT1, wT2, wT3, wT4, cpk, cc);
    // conv1 (fused transpose): x 1024 -> 505(512 rows) K=15, LeakyReLU
    k_conv1<<<dim3(4, 256), 256, 0, stream>>>(x, wT1, b1, h1);
    // conv2+conv3+conv4+dist fused: one block per n, 1024 threads (16 waves)
    k_fused234<<<256, 1024, 0, stream>>>(h1, wT2, wT3, wT4, b2, b3, b4, cpk, cc, out);
}

// Round 10
// 309.174 us; speedup vs baseline: 1.1088x; 1.1088x over previous
//
#include <hip/hip_runtime.h>

typedef __bf16 bf16;
typedef __bf16 bf16x4 __attribute__((ext_vector_type(4)));
typedef __bf16 bf16x8 __attribute__((ext_vector_type(8)));
typedef float f32x4 __attribute__((ext_vector_type(4)));

#define CCH 128  // channels (all layers 128 -> 128)

// ---- prep kernel 1: w1 only (conv1's dependency) ----
// packed[((kt*4 + c)*8 + og)*512 + lane*8 + e], o = og*16 + (lane&15),
// i = c*32 + (lane>>4)*8 + e  => A-fragment load = one contiguous 1KB burst.
__global__ void k_prep_w1(const float* __restrict__ w1, bf16* __restrict__ o1) {
    int r = blockIdx.x * 256 + threadIdx.x;   // [0, 15*16384)
    int e = r & 7, lane = (r >> 3) & 63, og = (r >> 9) & 7, c = (r >> 12) & 3, kt = r >> 14;
    int o = og * 16 + (lane & 15);
    int i = c * 32 + (lane >> 4) * 8 + e;
    o1[r] = (bf16)w1[(o * 128 + i) * 15 + kt];
}

// ---- kernel 2: conv1 (blocks 0..1023) + remaining prep (blocks 1024..2559) ----
// conv1 reads only x/wT1/b1 -> h1; prep-rest writes wT2/3/4, cbp, cc.
// Disjoint, so they share one dispatch; prep blocks fill scheduler slack.
__global__ __launch_bounds__(256, 4) void k_conv1p(
    const float* __restrict__ x, const bf16* __restrict__ wTp,
    const float* __restrict__ bias, bf16* __restrict__ out,
    const float* __restrict__ w2, const float* __restrict__ w3,
    const float* __restrict__ w4, const float* __restrict__ cen,
    bf16* __restrict__ o2, bf16* __restrict__ o3, bf16* __restrict__ o4,
    bf16* __restrict__ cbp, float* __restrict__ cc) {
    constexpr int KW = 15, LT = 128, PH = 2, OUT_ROWS = 512;
    constexpr int P = (LT - 1) * 2 + KW;   // 269 input positions needed
    constexpr int KC = 2;                  // 32-chunks per phase
    constexpr int RS = 64;                 // LDS row stride (elems)
    constexpr int NLT = LT / 16;           // 8
    constexpr int ESE = 136;               // epilogue [l][o] stride
    constexpr int SMELE = (P * RS > LT * ESE) ? P * RS : LT * ESE;  // 17408
    constexpr int NJ = KW * KC;            // 30
    __shared__ __align__(16) bf16 smem[SMELE];
    __shared__ float red[256];

    const int bid = blockIdx.x;
    const int tid = threadIdx.x;

    if (bid >= 1024) {
        // ---------------- prep-rest path ----------------
        int pb = bid - 1024;
        if (pb < 1472) {
            // wall pack for w2/w3/w4
            int r = pb * 256 + tid;   // [0, 23*16384)
            const float* src; bf16* dst; int Kw;
            if (r < 12 * 16384) { src = w2; dst = o2; Kw = 12; }
            else if ((r -= 12 * 16384) < 7 * 16384) { src = w3; dst = o3; Kw = 7; }
            else { r -= 7 * 16384; src = w4; dst = o4; Kw = 4; }
            int e = r & 7, lane = (r >> 3) & 63, og = (r >> 9) & 7, c = (r >> 12) & 3, kt = r >> 14;
            int o = og * 16 + (lane & 15);
            int i = c * 32 + (lane >> 4) * 8 + e;
            dst[r] = (bf16)src[(o * 128 + i) * Kw + kt];
        } else {
            // centers fp32 -> bf16 [k][l(64, zero-pad l>=59)][o], plus ||c||^2
            int k = pb - 1472;        // [0, 64)
            float s = 0.f;
            for (int idx = tid; idx < 64 * 128; idx += 256) {
                int l = idx >> 7;
                int o = idx & 127;
                float v = (l < 59) ? cen[k * 7552 + o * 59 + l] : 0.f;
                bf16 b = (bf16)v;
                cbp[(size_t)k * 64 * 128 + idx] = b;
                float fv = (float)b;
                s += fv * fv;
            }
            red[tid] = s;
            __syncthreads();
            for (int st = 128; st > 0; st >>= 1) {
                if (tid < st) red[tid] += red[tid + st];
                __syncthreads();
            }
            if (tid == 0) cc[k] = red[0];
        }
        return;
    }

    // ---------------- conv1 path (round-1 proven config, unchanged) ----------
    const int n = bid >> 2;
    const int l0 = (bid & 3) * LT;
    const int p0 = l0 * 2;
    const int wid = tid >> 6;
    const int lane = tid & 63;
    const int quad = lane >> 4;
    const int l15 = lane & 15;
    const int og0 = wid * 2;               // wave owns o [wid*32, wid*32+32)

    f32x4 acc[2][NLT];
#pragma unroll
    for (int a = 0; a < 2; ++a)
#pragma unroll
        for (int b = 0; b < NLT; ++b) acc[a][b] = (f32x4){0.f, 0.f, 0.f, 0.f};

    bf16x8 afr[2][2];
    const bf16* wbase = wTp + (size_t)lane * 8;
    afr[0][0] = *(const bf16x8*)(wbase + ((size_t)(og0 + 0) << 9));
    afr[0][1] = *(const bf16x8*)(wbase + ((size_t)(og0 + 1) << 9));

    const int cst = tid >> 2;              // channel within phase (0..63)
    const int qw = tid & 3;                // quad within 16-pos block

#pragma unroll 1
    for (int ph = 0; ph < PH; ++ph) {
        if (ph) __syncthreads();  // protect smem against overwrite

        const float* bch = x + ((size_t)(n * 128 + ph * 64 + cst)) * 1024;
#pragma unroll 4
        for (int it = 0; it < 17; ++it) {   // 17*16 = 272 positions (>=269)
            int pp = it * 16 + qw * 4;
            int gp = p0 + pp;
            f32x4 t;
            if (gp + 3 < 1024) {
                t = *(const f32x4*)(bch + gp);
            } else {
#pragma unroll
                for (int e = 0; e < 4; ++e) t[e] = (gp + e < 1024) ? bch[gp + e] : 0.f;
            }
#pragma unroll
            for (int e = 0; e < 4; ++e) {
                int ppe = pp + e;
                int sc8 = (((cst >> 3) ^ ((ppe >> 1) & 7)) << 3) | (cst & 7);
                smem[ppe * RS + sc8] = (bf16)t[e];
            }
        }
        __syncthreads();

#pragma unroll 2
        for (int j = 0; j < NJ; ++j) {
            int nj = j + 1, nph = ph;
            if (nj == NJ) { nj = 0; ++nph; }
            if (nph < PH) {
                int kt1 = nj >> 1;
                int c1 = (nj & (KC - 1)) + nph * KC;
                const bf16* wp = wbase + ((size_t)((kt1 * 4 + c1) * 8 + og0) << 9);
                afr[(j + 1) & 1][0] = *(const bf16x8*)(wp);
                afr[(j + 1) & 1][1] = *(const bf16x8*)(wp + 512);
            }
            const int kt = j >> 1;
            const int c16l = (j & (KC - 1)) * 4 + quad;
#pragma unroll
            for (int lt = 0; lt < NLT; ++lt) {
                int p = (lt * 16 + l15) * 2 + kt;
                int sc = c16l ^ ((p >> 1) & 7);
                bf16x8 bfr = *(const bf16x8*)(smem + p * RS + sc * 8);
                acc[0][lt] = __builtin_amdgcn_mfma_f32_16x16x32_bf16(
                    afr[j & 1][0], bfr, acc[0][lt], 0, 0, 0);
                acc[1][lt] = __builtin_amdgcn_mfma_f32_16x16x32_bf16(
                    afr[j & 1][1], bfr, acc[1][lt], 0, 0, 0);
            }
        }
    }

    __syncthreads();
#pragma unroll
    for (int ot = 0; ot < 2; ++ot) {
        const int o0 = wid * 32 + ot * 16 + quad * 4;
        const f32x4 bv = *(const f32x4*)(bias + o0);
#pragma unroll
        for (int lt = 0; lt < NLT; ++lt) {
            const int l = lt * 16 + l15;
            bf16x4 pk;
#pragma unroll
            for (int r = 0; r < 4; ++r) {
                float v = acc[ot][lt][r] + bv[r];
                v = (v > 0.f) ? v : 0.1f * v;
                pk[r] = (bf16)v;
            }
            *(bf16x4*)(smem + l * ESE + o0) = pk;
        }
    }
    __syncthreads();
    constexpr int SNIT = LT * 16 / 256;
    bf16* op = out + ((size_t)n * OUT_ROWS + l0) * CCH;
#pragma unroll
    for (int it = 0; it < SNIT; ++it) {
        int u = tid + it * 256;
        int l = u >> 4;
        int g = u & 15;
        *(bf16x8*)(op + l * CCH + g * 8) = *(const bf16x8*)(smem + l * ESE + g * 8);
    }
}

// ---- fused conv2+conv3+conv4+distances: ONE block per n, 512 threads ----
// (round-5 proven-best configuration, verbatim)
__global__ __launch_bounds__(512, 1) void k_fused234(
    const bf16* __restrict__ h1g, const bf16* __restrict__ wT2,
    const bf16* __restrict__ wT3, const bf16* __restrict__ wT4,
    const float* __restrict__ b2, const float* __restrict__ b3,
    const float* __restrict__ b4, const bf16* __restrict__ cbp,
    const float* __restrict__ cc, float* __restrict__ out) {
    // LDS plan (bf16 elems):
    //  region A (34048 el = 68KB): sbuf 266 rows x128 during conv2;
    //                              then h3 (130 rows x128 = 16640) + zmem (64x136)
    //  region B (33536 el = 67KB): h2 262 rows x128 (rows 256.. zero-initialized)
    __shared__ __align__(16) bf16 lds[34048 + 33536];
    __shared__ float d2s[64];
    bf16* sbuf = lds;
    bf16* h2   = lds + 34048;
    bf16* h3   = lds;           // after conv2
    bf16* zmem = lds + 16640;   // after conv2

    const int n = blockIdx.x;
    const int tid = threadIdx.x;
    const int wid = tid >> 6;     // 0..7
    const int lane = tid & 63;
    const int quad = lane >> 4;
    const int l15 = lane & 15;

    // zero junk h2 rows 256..261 (read by conv3 tail, never written)
    if (tid < 96) *(f32x4*)(h2 + 256 * 128 + tid * 8) = (f32x4){0.f, 0.f, 0.f, 0.f};

    // ================= conv2: h1(global) -> h2(LDS), K=12, LeakyReLU ======
    // two 64-row tiles computed concurrently per stage: wavegroup g=wid>>2
    // owns tile 2s+g; within group: w4=wid&3 -> og pair, all 64 rows (NLT=4).
    {
        const int w4 = wid & 3;
        const int g = wid >> 2;
        const int og0 = w4 * 2;
        const bf16* w2base = wT2 + (size_t)lane * 8;
        constexpr int NJ2 = 48;                 // 12 kt x 4 c
#pragma unroll 1
        for (int s = 0; s < 2; ++s) {
            if (s) __syncthreads();
            // stage h1 rows [s*256, s*256+266) -> sbuf (local rows 0..265),
            // write-side XOR swizzle (same pattern as k_conv staging)
            {
                const bf16* base = h1g + (size_t)n * 512 * 128;
#pragma unroll
                for (int it = 0; it < 9; ++it) {
                    int u = tid + it * 512;
                    if (u < 266 * 16) {
                        int p = u >> 4, c = u & 15;
                        int prow = s * 256 + p; if (prow > 511) prow = 511;
                        bf16x8 t = *(const bf16x8*)(base + (size_t)prow * 128 + c * 8);
                        int sc = (c & 8) | ((c & 7) ^ ((p >> 1) & 7));
                        *(bf16x8*)(sbuf + p * 128 + sc * 8) = t;
                    }
                }
            }
            __syncthreads();

            f32x4 acc[2][4];
#pragma unroll
            for (int a = 0; a < 2; ++a)
#pragma unroll
                for (int b = 0; b < 4; ++b) acc[a][b] = (f32x4){0.f, 0.f, 0.f, 0.f};
            bf16x8 afr[2][2];
            afr[0][0] = *(const bf16x8*)(w2base + ((size_t)og0 << 9));
            afr[0][1] = *(const bf16x8*)(w2base + ((size_t)(og0 + 1) << 9));
#pragma unroll 2
            for (int j = 0; j < NJ2; ++j) {
                if (j + 1 < NJ2) {
                    int kt1 = (j + 1) >> 2, c1 = (j + 1) & 3;
                    const bf16* wp = w2base + ((size_t)((kt1 * 4 + c1) * 8 + og0) << 9);
                    afr[(j + 1) & 1][0] = *(const bf16x8*)(wp);
                    afr[(j + 1) & 1][1] = *(const bf16x8*)(wp + 512);
                }
                int kt = j >> 2;
                int c16l = (j & 3) * 4 + quad;
#pragma unroll
                for (int lt = 0; lt < 4; ++lt) {
                    int p = (g * 64 + lt * 16 + l15) * 2 + kt;   // local sbuf row
                    int sc = (c16l & 8) | ((c16l & 7) ^ ((p >> 1) & 7));
                    bf16x8 bfr = *(const bf16x8*)(sbuf + p * 128 + sc * 8);
                    acc[0][lt] = __builtin_amdgcn_mfma_f32_16x16x32_bf16(
                        afr[j & 1][0], bfr, acc[0][lt], 0, 0, 0);
                    acc[1][lt] = __builtin_amdgcn_mfma_f32_16x16x32_bf16(
                        afr[j & 1][1], bfr, acc[1][lt], 0, 0, 0);
                }
            }
            // epilogue -> h2 (swizzled layout conv3 expects), LeakyReLU
#pragma unroll
            for (int ot = 0; ot < 2; ++ot) {
                int o0 = (og0 + ot) * 16 + quad * 4;
                f32x4 bv = *(const f32x4*)(b2 + o0);
                int c = o0 >> 3;
#pragma unroll
                for (int lt = 0; lt < 4; ++lt) {
                    int l = s * 128 + g * 64 + lt * 16 + l15;   // h2 row 0..255
                    bf16x4 pk;
#pragma unroll
                    for (int r = 0; r < 4; ++r) {
                        float v = acc[ot][lt][r] + bv[r];
                        v = (v > 0.f) ? v : 0.1f * v;
                        pk[r] = (bf16)v;
                    }
                    int sc = (c & 8) | ((c & 7) ^ ((l >> 1) & 7));
                    *(bf16x4*)(h2 + l * 128 + sc * 8 + (o0 & 7)) = pk;
                }
            }
            __syncthreads();
        }
    }

    // ================= conv3: h2(LDS) -> h3(LDS), K=7, LeakyReLU ==========
    {
        // zero junk h3 rows 128..129 (read by conv4 tail)
        if (tid < 32) *(f32x4*)(h3 + 128 * 128 + tid * 8) = (f32x4){0.f, 0.f, 0.f, 0.f};
        const int og0 = (wid & 3) * 2;
        const int ph3 = wid >> 2;            // 64-row half
        const bf16* w3base = wT3 + (size_t)lane * 8;
        constexpr int NJ3 = 28;              // 7 kt x 4 c
        f32x4 acc[2][4];
#pragma unroll
        for (int a = 0; a < 2; ++a)
#pragma unroll
            for (int b = 0; b < 4; ++b) acc[a][b] = (f32x4){0.f, 0.f, 0.f, 0.f};
        bf16x8 afr[2][2];
        afr[0][0] = *(const bf16x8*)(w3base + ((size_t)og0 << 9));
        afr[0][1] = *(const bf16x8*)(w3base + ((size_t)(og0 + 1) << 9));
#pragma unroll 2
        for (int j = 0; j < NJ3; ++j) {
            if (j + 1 < NJ3) {
                int kt1 = (j + 1) >> 2, c1 = (j + 1) & 3;
                const bf16* wp = w3base + ((size_t)((kt1 * 4 + c1) * 8 + og0) << 9);
                afr[(j + 1) & 1][0] = *(const bf16x8*)(wp);
                afr[(j + 1) & 1][1] = *(const bf16x8*)(wp + 512);
            }
            int kt = j >> 2;
            int c16l = (j & 3) * 4 + quad;
#pragma unroll
            for (int lt = 0; lt < 4; ++lt) {
                int p = (ph3 * 64 + lt * 16 + l15) * 2 + kt;   // h2 row <= 260
                int sc = (c16l & 8) | ((c16l & 7) ^ ((p >> 1) & 7));
                bf16x8 bfr = *(const bf16x8*)(h2 + p * 128 + sc * 8);
                acc[0][lt] = __builtin_amdgcn_mfma_f32_16x16x32_bf16(
                    afr[j & 1][0], bfr, acc[0][lt], 0, 0, 0);
                acc[1][lt] = __builtin_amdgcn_mfma_f32_16x16x32_bf16(
                    afr[j & 1][1], bfr, acc[1][lt], 0, 0, 0);
            }
        }
        __syncthreads();   // sbuf (region A) dead; safe to write h3
        // epilogue -> h3 (swizzled layout conv4 expects), LeakyReLU
#pragma unroll
        for (int ot = 0; ot < 2; ++ot) {
            int o0 = (og0 + ot) * 16 + quad * 4;
            f32x4 bv = *(const f32x4*)(b3 + o0);
            int c = o0 >> 3;
#pragma unroll
            for (int lt = 0; lt < 4; ++lt) {
                int l = ph3 * 64 + lt * 16 + l15;   // h3 row 0..127
                bf16x4 pk;
#pragma unroll
                for (int r = 0; r < 4; ++r) {
                    float v = acc[ot][lt][r] + bv[r];
                    v = (v > 0.f) ? v : 0.1f * v;
                    pk[r] = (bf16)v;
                }
                int sc = (c & 8) | ((c & 7) ^ ((l >> 1) & 7));
                *(bf16x4*)(h3 + l * 128 + sc * 8 + (o0 & 7)) = pk;
            }
        }
    }
    __syncthreads();

    // ================= conv4: h3(LDS) -> zmem, no act, zero-pad l>=59 =====
    {
        f32x4 acc[4];
#pragma unroll
        for (int b = 0; b < 4; ++b) acc[b] = (f32x4){0.f, 0.f, 0.f, 0.f};
        bf16x8 afr[2];
        const bf16* w4base = wT4 + (size_t)lane * 8;
        afr[0] = *(const bf16x8*)(w4base + ((size_t)wid << 9));  // kt=0,c=0,og=wid
        constexpr int NJ4 = 16;              // 4 kt x 4 c
#pragma unroll 2
        for (int j = 0; j < NJ4; ++j) {
            if (j + 1 < NJ4) {
                int kt1 = (j + 1) >> 2, c1 = (j + 1) & 3;
                afr[(j + 1) & 1] =
                    *(const bf16x8*)(w4base + ((size_t)((kt1 * 4 + c1) * 8 + wid) << 9));
            }
            int kt = j >> 2;
            int c16l = (j & 3) * 4 + quad;
#pragma unroll
            for (int lt = 0; lt < 4; ++lt) {
                int p = (lt * 16 + l15) * 2 + kt;   // h3 row <= 129
                int sc = (c16l & 8) | ((c16l & 7) ^ ((p >> 1) & 7));
                bf16x8 bfr = *(const bf16x8*)(h3 + p * 128 + sc * 8);
                acc[lt] = __builtin_amdgcn_mfma_f32_16x16x32_bf16(afr[j & 1], bfr, acc[lt], 0, 0, 0);
            }
        }
        // epilogue -> z bf16 [l][o] (ESE=136), zeros l>=59
        const int o0 = wid * 16 + quad * 4;
        const f32x4 bv = *(const f32x4*)(b4 + o0);
#pragma unroll
        for (int lt = 0; lt < 4; ++lt) {
            const int l = lt * 16 + l15;
            bf16x4 pk;
#pragma unroll
            for (int r = 0; r < 4; ++r) {
                float v = acc[lt][r] + bv[r];
                pk[r] = (l < 59) ? (bf16)v : (bf16)0.f;
            }
            *(bf16x4*)(zmem + l * 136 + o0) = pk;
        }
    }
    __syncthreads();

    // ================= distances + Student-t assignment ===================
#pragma unroll 1
    for (int cp = 0; cp < 8; ++cp) {
        const int kc = cp * 8 + wid;
        const bf16* cr = cbp + (size_t)kc * 8192;
        float t = 0.f;
#pragma unroll
        for (int it = 0; it < 16; ++it) {
            int ci = it * 64 + lane;
            int l = ci >> 4;
            int g = ci & 15;
            bf16x8 cv = *(const bf16x8*)(cr + ci * 8);
            bf16x8 zv = *(const bf16x8*)(zmem + l * 136 + g * 8);
#pragma unroll
            for (int e = 0; e < 8; ++e) {
                float zf = (float)zv[e];
                t += zf * (zf - 2.f * (float)cv[e]);
            }
        }
#pragma unroll
        for (int o = 32; o > 0; o >>= 1) t += __shfl_xor(t, o);
        if (lane == 0) d2s[kc] = t + cc[kc];
    }
    __syncthreads();
    if (tid < 64) {
        float q = 1.f / (1.f + d2s[tid]);  // ALPHA=1, exponent (ALPHA+1)/2 == 1
        float tot = q;
#pragma unroll
        for (int o = 32; o > 0; o >>= 1) tot += __shfl_xor(tot, o);
        out[n * 64 + tid] = q / tot;
    }
}

// ---------------- launcher ----------------
extern "C" void kernel_launch(void* const* d_in, const int* in_sizes, int n_in,
                              void* d_out, int out_size, void* d_ws, size_t ws_size,
                              hipStream_t stream) {
    (void)in_sizes; (void)n_in; (void)out_size; (void)ws_size;
    const float* x   = (const float*)d_in[0];
    const float* w1  = (const float*)d_in[1];
    const float* b1  = (const float*)d_in[2];
    const float* w2  = (const float*)d_in[3];
    const float* b2  = (const float*)d_in[4];
    const float* w3  = (const float*)d_in[5];
    const float* b3  = (const float*)d_in[6];
    const float* w4  = (const float*)d_in[7];
    const float* b4  = (const float*)d_in[8];
    const float* cen = (const float*)d_in[9];
    float* out = (float*)d_out;

    char* ws = (char*)d_ws;
    size_t off = 0;
    auto alloc = [&](size_t bytes) -> void* {
        void* p = ws + off;
        off += (bytes + 255) & ~(size_t)255;
        return p;
    };
    bf16* wT1 = (bf16*)alloc((size_t)15 * 16384 * sizeof(bf16));
    bf16* wT2 = (bf16*)alloc((size_t)12 * 16384 * sizeof(bf16));
    bf16* wT3 = (bf16*)alloc((size_t)7 * 16384 * sizeof(bf16));
    bf16* wT4 = (bf16*)alloc((size_t)4 * 16384 * sizeof(bf16));
    bf16* cbp = (bf16*)alloc((size_t)64 * 64 * 128 * sizeof(bf16));
    float* cc = (float*)alloc(64 * sizeof(float));
    bf16* h1  = (bf16*)alloc((size_t)256 * 512 * 128 * sizeof(bf16));
    (void)alloc((size_t)1 << 20);  // slack: tile overreads stay in-bounds

    // 1) tiny: pack w1 only (conv1's sole prep dependency)
    k_prep_w1<<<960, 256, 0, stream>>>(w1, wT1);
    // 2) conv1 (1024 blocks) + prep-rest (1472 wall + 64 center blocks) merged
    k_conv1p<<<1024 + 1472 + 64, 256, 0, stream>>>(
        x, wT1, b1, h1, w2, w3, w4, cen, wT2, wT3, wT4, cbp, cc);
    // 3) conv2+conv3+conv4+dist fused (round-5 proven config)
    k_fused234<<<256, 512, 0, stream>>>(h1, wT2, wT3, wT4, b2, b3, b4, cbp, cc, out);
}